// Round 7
// baseline (218.628 us; speedup 1.0000x reference)
//
#include <hip/hip_runtime.h>
#include <stdint.h>

// ReconstructionDecoder: out[b,n,t,f,:] = relu(LN(x[b,n]+t_emb[t]+f_emb[f]) @ W1 + b1) @ W2 + b2
// B=2 N=8 T=128 F=128 D=256 E=512.  Rows M = 262144.
//
// Round 7: occupancy-cap fix. Empirical law from r1-r6: measured occupancy == 4 * (2nd
// __launch_bounds__ arg) waves/CU, ALWAYS (44% @4, 21.5% @2, 21-23% @1-2) -> the min-waves
// hint acts as a hard occupancy CAP on this ROCm. r3/r6 ran ~2 blocks/CU; barrier-step
// latency (~1.5-2.4k cyc) had nothing to backfill -> MfmaUtil 17-22%.
// Fix: __launch_bounds__(256) with NO min-waves arg. Natural VGPR (~96-128) -> 4 waves/SIMD
// -> 16 waves/CU = 4 resident blocks (4 x 24KB LDS = 96KB <= 160KB).
// Everything else identical to r6 (the only proven no-spill shape: afrag[2][8], 24KB LDS,
// 32 steps x {2 global_load_lds + 8 ds_read_b128 + 16 MFMA}, 1 barrier/step).

#define D_ 256
#define E_ 512

typedef __attribute__((ext_vector_type(8))) short short8;
typedef __attribute__((ext_vector_type(4))) float f32x4;

typedef __attribute__((address_space(1))) void gvoid;
typedef __attribute__((address_space(3))) void lvoid;
#define GLOAD_LDS16(g, l) \
  __builtin_amdgcn_global_load_lds((gvoid*)(g), (lvoid*)(l), 16, 0, 0)

__device__ inline unsigned short f2bf(float f) {
  unsigned int u = __float_as_uint(f);
  u += 0x7fffu + ((u >> 16) & 1u);
  return (unsigned short)(u >> 16);
}

// prep: blocks 0..127  -> w1t[e][k] = bf16(ln_g[k]*W1[k][e]) (4 e-rows per block)
//       blocks 128..159 -> b1p[e] = b1[e] + sum_k ln_b[k]*W1[k][e] (16 e per block)
__global__ __launch_bounds__(256) void prep(const float* __restrict__ W1,
                                            const float* __restrict__ ln_g,
                                            const float* __restrict__ ln_b,
                                            const float* __restrict__ b1,
                                            unsigned short* __restrict__ w1t,
                                            float* __restrict__ b1p) {
  __shared__ float s[256 * 5];
  const int blk = blockIdx.x;
  const int tid = threadIdx.x;
  if (blk < 128) {
    const int e0 = blk * 4;
    // read: thread t = k reads 4 consecutive e (16B), scales by ln_g[k]
    float4 w = *reinterpret_cast<const float4*>(W1 + tid * E_ + e0);
    float g = ln_g[tid];
    s[tid * 5 + 0] = w.x * g;
    s[tid * 5 + 1] = w.y * g;
    s[tid * 5 + 2] = w.z * g;
    s[tid * 5 + 3] = w.w * g;
    __syncthreads();
    // write: 16B granules of 8 consecutive k within one e-row
    if (tid < 128) {
      int e = tid >> 5, k0 = (tid & 31) * 8;
      union { unsigned short u[8]; float4 v; } pk;
#pragma unroll
      for (int j = 0; j < 8; ++j) pk.u[j] = f2bf(s[(k0 + j) * 5 + e]);
      *reinterpret_cast<float4*>(w1t + (e0 + e) * D_ + k0) = pk.v;
    }
  } else {
    int bb = blk - 128;        // 0..31, 16 e's per block
    int e = bb * 16 + (tid & 15);
    int kb = (tid >> 4) * 16;  // 16 threads per e, 16 k's per thread
    float p = 0.f;
    for (int i = 0; i < 16; ++i) p = fmaf(ln_b[kb + i], W1[(kb + i) * E_ + e], p);
    s[tid] = p;
    __syncthreads();
    if (tid < 16) {
      float ssum = b1[bb * 16 + tid];
      for (int g = 0; g < 16; ++g) ssum += s[g * 16 + tid];
      b1p[bb * 16 + tid] = ssum;
    }
  }
}

__global__ __launch_bounds__(256) void decoder_main(
    const float* __restrict__ x, const float* __restrict__ t_emb,
    const float* __restrict__ f_emb, const unsigned short* __restrict__ w1t,
    const float* __restrict__ b1p, const float* __restrict__ W2,
    const float* __restrict__ b2, float* __restrict__ out) {
  __shared__ short8 s_frag[2][512];  // 2 x 8KB ping-pong: one 16-e chunk each
  __shared__ float s_xt[D_];         // 1KB: x[b,n,:] + t_emb[t,:]
  __shared__ float s_b1[E_];         // 2KB
  __shared__ float s_w2[2 * E_];     // 4KB
  __shared__ float s_out[256];       // 1KB   (total 24KB -> 4 blocks/CU w/ 16 waves)

  const int tid = threadIdx.x;
  const int wave = tid >> 6;
  const int lane = tid & 63;
  const int quad = (lane >> 4) & 3;
  const int n16 = lane & 15;
  const int bIdx = blockIdx.x;  // (b*8+n)*128 + t  -> block covers f=0..127
  const int bn = bIdx >> 7;
  const int t = bIdx & 127;

  // stage chunk c (16 e-cols x 256 k = 8KB) into nb; wave covers ks = 2*wave, 2*wave+1
  auto stage = [&](int c, short8* nb) {
#pragma unroll
    for (int i = 0; i < 2; ++i) {
      int ks = wave * 2 + i;
      GLOAD_LDS16(w1t + (c * 16 + n16) * D_ + ks * 32 + quad * 8, nb + ks * 64);
    }
  };
  stage(0, s_frag[0]);  // flies during constant staging + A-build

  // cooperative stage of per-block constants
  s_xt[tid] = x[bn * D_ + tid] + t_emb[t * D_ + tid];
  s_b1[tid] = b1p[tid];
  s_b1[tid + 256] = b1p[tid + 256];
  s_w2[tid] = W2[tid];
  s_w2[tid + 256] = W2[tid + 256];
  s_w2[tid + 512] = W2[tid + 512];
  s_w2[tid + 768] = W2[tid + 768];
  __syncthreads();

  // ---- build A fragments (LN-normalized h, bf16) for 2 row-groups of 16 ----
  short8 afrag[2][8];
#pragma unroll
  for (int g = 0; g < 2; ++g) {
    const int f = wave * 32 + g * 16 + n16;
    const float4* fe = reinterpret_cast<const float4*>(f_emb + f * D_);
    const float4* xt4 = reinterpret_cast<const float4*>(s_xt);
    float sum = 0.f, sq = 0.f;
#pragma unroll
    for (int ks = 0; ks < 8; ++ks) {
      int i0 = ks * 8 + quad * 2;
      float4 a0 = xt4[i0], a1 = xt4[i0 + 1];
      float4 c0 = fe[i0], c1 = fe[i0 + 1];
      float h0 = a0.x + c0.x, h1 = a0.y + c0.y, h2 = a0.z + c0.z, h3 = a0.w + c0.w;
      float h4 = a1.x + c1.x, h5 = a1.y + c1.y, h6 = a1.z + c1.z, h7 = a1.w + c1.w;
      sum += (h0 + h1 + h2 + h3) + (h4 + h5 + h6 + h7);
      sq = fmaf(h0, h0, sq); sq = fmaf(h1, h1, sq);
      sq = fmaf(h2, h2, sq); sq = fmaf(h3, h3, sq);
      sq = fmaf(h4, h4, sq); sq = fmaf(h5, h5, sq);
      sq = fmaf(h6, h6, sq); sq = fmaf(h7, h7, sq);
    }
    // row's 256 elems live in lanes {l, l^16, l^32, l^48}
    sum += __shfl_xor(sum, 16); sum += __shfl_xor(sum, 32);
    sq  += __shfl_xor(sq, 16);  sq  += __shfl_xor(sq, 32);
    float mu = sum * (1.0f / 256.0f);
    float var = sq * (1.0f / 256.0f) - mu * mu;
    float rs = rsqrtf(var + 1e-5f);
    float cc = -mu * rs;
#pragma unroll
    for (int ks = 0; ks < 8; ++ks) {
      int i0 = ks * 8 + quad * 2;
      float4 a0 = xt4[i0], a1 = xt4[i0 + 1];
      float4 c0 = fe[i0], c1 = fe[i0 + 1];
      union { unsigned short u[8]; short8 v; } fr;
      fr.u[0] = f2bf(fmaf(a0.x + c0.x, rs, cc));
      fr.u[1] = f2bf(fmaf(a0.y + c0.y, rs, cc));
      fr.u[2] = f2bf(fmaf(a0.z + c0.z, rs, cc));
      fr.u[3] = f2bf(fmaf(a0.w + c0.w, rs, cc));
      fr.u[4] = f2bf(fmaf(a1.x + c1.x, rs, cc));
      fr.u[5] = f2bf(fmaf(a1.y + c1.y, rs, cc));
      fr.u[6] = f2bf(fmaf(a1.z + c1.z, rs, cc));
      fr.u[7] = f2bf(fmaf(a1.w + c1.w, rs, cc));
      afrag[g][ks] = fr.v;
    }
  }

  // ---- main loop: 32 chunks x (8 K-steps x 2 row-groups), 1 barrier per chunk ----
  float oa[2][4][2] = {};
  for (int s = 0; s < 32; ++s) {
    __syncthreads();  // buf[s&1] loads drained + all waves past buf[(s+1)&1] reads
    if (s < 31) stage(s + 1, s_frag[(s + 1) & 1]);
    const short8* bf8 = s_frag[s & 1];
    f32x4 acc0 = {0.f, 0.f, 0.f, 0.f};
    f32x4 acc1 = {0.f, 0.f, 0.f, 0.f};
#pragma unroll
    for (int ks = 0; ks < 8; ++ks) {
      short8 bf = bf8[ks * 64 + lane];
      acc0 = __builtin_amdgcn_mfma_f32_16x16x32_bf16(afrag[0][ks], bf, acc0, 0, 0, 0);
      acc1 = __builtin_amdgcn_mfma_f32_16x16x32_bf16(afrag[1][ks], bf, acc1, 0, 0, 0);
    }
    int e = s * 16 + n16;
    float bias = s_b1[e];
    float w0 = s_w2[2 * e], w1v = s_w2[2 * e + 1];
#pragma unroll
    for (int r = 0; r < 4; ++r) {
      float y0 = fmaxf(acc0[r] + bias, 0.f);
      float y1 = fmaxf(acc1[r] + bias, 0.f);
      oa[0][r][0] += y0 * w0; oa[0][r][1] += y0 * w1v;
      oa[1][r][0] += y1 * w0; oa[1][r][1] += y1 * w1v;
    }
  }

  // ---- reduce over the 16 column-lanes, stage, coalesced store ----
#pragma unroll
  for (int g = 0; g < 2; ++g)
#pragma unroll
    for (int r = 0; r < 4; ++r)
#pragma unroll
      for (int o = 0; o < 2; ++o) {
        float v = oa[g][r][o];
        v += __shfl_xor(v, 1);
        v += __shfl_xor(v, 2);
        v += __shfl_xor(v, 4);
        v += __shfl_xor(v, 8);
        oa[g][r][o] = v;
      }
  if (n16 == 0) {
#pragma unroll
    for (int g = 0; g < 2; ++g)
#pragma unroll
      for (int r = 0; r < 4; ++r) {
        int lrow = wave * 32 + g * 16 + quad * 4 + r;  // = f
        s_out[lrow * 2 + 0] = oa[g][r][0];
        s_out[lrow * 2 + 1] = oa[g][r][1];
      }
  }
  __syncthreads();
  out[bIdx * 256 + tid] = s_out[tid] + b2[tid & 1];
}

extern "C" void kernel_launch(void* const* d_in, const int* in_sizes, int n_in,
                              void* d_out, int out_size, void* d_ws, size_t ws_size,
                              hipStream_t stream) {
  const float* x = (const float*)d_in[0];
  const float* t_emb = (const float*)d_in[1];
  const float* f_emb = (const float*)d_in[2];
  const float* ln_g = (const float*)d_in[3];
  const float* ln_b = (const float*)d_in[4];
  const float* W1 = (const float*)d_in[5];
  const float* b1 = (const float*)d_in[6];
  const float* W2 = (const float*)d_in[7];
  const float* b2 = (const float*)d_in[8];

  unsigned short* w1t = (unsigned short*)d_ws;      // 512x256 bf16 = 256KB
  float* b1p = (float*)((char*)d_ws + 131072 * 2);  // 2KB

  prep<<<160, 256, 0, stream>>>(W1, ln_g, ln_b, b1, w1t, b1p);
  decoder_main<<<2048, 256, 0, stream>>>(x, t_emb, f_emb, w1t, b1p, W2, b2,
                                         (float*)d_out);
}

// Round 8
// 194.150 us; speedup vs baseline: 1.1261x; 1.1261x over previous
//
#include <hip/hip_runtime.h>
#include <stdint.h>

// ReconstructionDecoder: out[b,n,t,f,:] = relu(LN(x[b,n]+t_emb[t]+f_emb[f]) @ W1 + b1) @ W2 + b2
// B=2 N=8 T=128 F=128 D=256 E=512.  Rows M = 262144.
//
// Round 8: kill the per-step vmcnt(0) serialization. r6/r7 step time = 1.55k cyc vs ~350 cyc
// of work: stage(s+1) was issued BEFORE the ds_reads of chunk s, so the memory legalizer
// (unable to disambiguate ping-pong LDS buffers) put s_waitcnt vmcnt(0) in front of the
// ds_reads -> every step synchronously ate the full load flight time.
// Fix (minimal diff from r7):
//  - iteration order: barrier -> compute(s) -> stage(s+2). After the barrier's drain there
//    are ZERO outstanding vmem ops when ds_reads issue -> no vmcnt wait before them.
//  - stage TWO ahead into 4 ping-pong buffers (32KB): chunk s's loads issued at iter s-2,
//    force-drained at iter s-1's barrier with ~one compute window (~300cyc) of slack >= L2
//    latency. Buffer reuse separated by 2 barriers -> race-free.
//  - LDS exactly 40KB (4 blocks/CU possible), registers unchanged (~112, proven no-spill).

#define D_ 256
#define E_ 512

typedef __attribute__((ext_vector_type(8))) short short8;
typedef __attribute__((ext_vector_type(4))) float f32x4;

typedef __attribute__((address_space(1))) void gvoid;
typedef __attribute__((address_space(3))) void lvoid;
#define GLOAD_LDS16(g, l) \
  __builtin_amdgcn_global_load_lds((gvoid*)(g), (lvoid*)(l), 16, 0, 0)

__device__ inline unsigned short f2bf(float f) {
  unsigned int u = __float_as_uint(f);
  u += 0x7fffu + ((u >> 16) & 1u);
  return (unsigned short)(u >> 16);
}

// prep: blocks 0..127  -> w1t[e][k] = bf16(ln_g[k]*W1[k][e]) (4 e-rows per block)
//       blocks 128..159 -> b1p[e] = b1[e] + sum_k ln_b[k]*W1[k][e] (16 e per block)
__global__ __launch_bounds__(256) void prep(const float* __restrict__ W1,
                                            const float* __restrict__ ln_g,
                                            const float* __restrict__ ln_b,
                                            const float* __restrict__ b1,
                                            unsigned short* __restrict__ w1t,
                                            float* __restrict__ b1p) {
  __shared__ float s[256 * 5];
  const int blk = blockIdx.x;
  const int tid = threadIdx.x;
  if (blk < 128) {
    const int e0 = blk * 4;
    // read: thread t = k reads 4 consecutive e (16B), scales by ln_g[k]
    float4 w = *reinterpret_cast<const float4*>(W1 + tid * E_ + e0);
    float g = ln_g[tid];
    s[tid * 5 + 0] = w.x * g;
    s[tid * 5 + 1] = w.y * g;
    s[tid * 5 + 2] = w.z * g;
    s[tid * 5 + 3] = w.w * g;
    __syncthreads();
    // write: 16B granules of 8 consecutive k within one e-row
    if (tid < 128) {
      int e = tid >> 5, k0 = (tid & 31) * 8;
      union { unsigned short u[8]; float4 v; } pk;
#pragma unroll
      for (int j = 0; j < 8; ++j) pk.u[j] = f2bf(s[(k0 + j) * 5 + e]);
      *reinterpret_cast<float4*>(w1t + (e0 + e) * D_ + k0) = pk.v;
    }
  } else {
    int bb = blk - 128;        // 0..31, 16 e's per block
    int e = bb * 16 + (tid & 15);
    int kb = (tid >> 4) * 16;  // 16 threads per e, 16 k's per thread
    float p = 0.f;
    for (int i = 0; i < 16; ++i) p = fmaf(ln_b[kb + i], W1[(kb + i) * E_ + e], p);
    s[tid] = p;
    __syncthreads();
    if (tid < 16) {
      float ssum = b1[bb * 16 + tid];
      for (int g = 0; g < 16; ++g) ssum += s[g * 16 + tid];
      b1p[bb * 16 + tid] = ssum;
    }
  }
}

__global__ __launch_bounds__(256) void decoder_main(
    const float* __restrict__ x, const float* __restrict__ t_emb,
    const float* __restrict__ f_emb, const unsigned short* __restrict__ w1t,
    const float* __restrict__ b1p, const float* __restrict__ W2,
    const float* __restrict__ b2, float* __restrict__ out) {
  __shared__ short8 s_frag[4][512];  // 4 x 8KB rotating: 16-e chunks, staged 2 ahead
  __shared__ float s_xt[D_];         // 1KB: x[b,n,:] + t_emb[t,:]
  __shared__ float s_b1[E_];         // 2KB
  __shared__ float s_w2[2 * E_];     // 4KB
  __shared__ float s_out[256];       // 1KB   (total exactly 40KB -> 4 blocks/CU by LDS)

  const int tid = threadIdx.x;
  const int wave = tid >> 6;
  const int lane = tid & 63;
  const int quad = (lane >> 4) & 3;
  const int n16 = lane & 15;
  const int bIdx = blockIdx.x;  // (b*8+n)*128 + t  -> block covers f=0..127
  const int bn = bIdx >> 7;
  const int t = bIdx & 127;

  // stage chunk c (16 e-cols x 256 k = 8KB) into nb; wave covers ks = 2*wave, 2*wave+1
  auto stage = [&](int c, short8* nb) {
#pragma unroll
    for (int i = 0; i < 2; ++i) {
      int ks = wave * 2 + i;
      GLOAD_LDS16(w1t + (c * 16 + n16) * D_ + ks * 32 + quad * 8, nb + ks * 64);
    }
  };
  stage(0, s_frag[0]);  // chunks 0,1 fly during constant staging + A-build
  stage(1, s_frag[1]);

  // cooperative stage of per-block constants
  s_xt[tid] = x[bn * D_ + tid] + t_emb[t * D_ + tid];
  s_b1[tid] = b1p[tid];
  s_b1[tid + 256] = b1p[tid + 256];
  s_w2[tid] = W2[tid];
  s_w2[tid + 256] = W2[tid + 256];
  s_w2[tid + 512] = W2[tid + 512];
  s_w2[tid + 768] = W2[tid + 768];
  __syncthreads();

  // ---- build A fragments (LN-normalized h, bf16) for 2 row-groups of 16 ----
  short8 afrag[2][8];
#pragma unroll
  for (int g = 0; g < 2; ++g) {
    const int f = wave * 32 + g * 16 + n16;
    const float4* fe = reinterpret_cast<const float4*>(f_emb + f * D_);
    const float4* xt4 = reinterpret_cast<const float4*>(s_xt);
    float sum = 0.f, sq = 0.f;
#pragma unroll
    for (int ks = 0; ks < 8; ++ks) {
      int i0 = ks * 8 + quad * 2;
      float4 a0 = xt4[i0], a1 = xt4[i0 + 1];
      float4 c0 = fe[i0], c1 = fe[i0 + 1];
      float h0 = a0.x + c0.x, h1 = a0.y + c0.y, h2 = a0.z + c0.z, h3 = a0.w + c0.w;
      float h4 = a1.x + c1.x, h5 = a1.y + c1.y, h6 = a1.z + c1.z, h7 = a1.w + c1.w;
      sum += (h0 + h1 + h2 + h3) + (h4 + h5 + h6 + h7);
      sq = fmaf(h0, h0, sq); sq = fmaf(h1, h1, sq);
      sq = fmaf(h2, h2, sq); sq = fmaf(h3, h3, sq);
      sq = fmaf(h4, h4, sq); sq = fmaf(h5, h5, sq);
      sq = fmaf(h6, h6, sq); sq = fmaf(h7, h7, sq);
    }
    // row's 256 elems live in lanes {l, l^16, l^32, l^48}
    sum += __shfl_xor(sum, 16); sum += __shfl_xor(sum, 32);
    sq  += __shfl_xor(sq, 16);  sq  += __shfl_xor(sq, 32);
    float mu = sum * (1.0f / 256.0f);
    float var = sq * (1.0f / 256.0f) - mu * mu;
    float rs = rsqrtf(var + 1e-5f);
    float cc = -mu * rs;
#pragma unroll
    for (int ks = 0; ks < 8; ++ks) {
      int i0 = ks * 8 + quad * 2;
      float4 a0 = xt4[i0], a1 = xt4[i0 + 1];
      float4 c0 = fe[i0], c1 = fe[i0 + 1];
      union { unsigned short u[8]; short8 v; } fr;
      fr.u[0] = f2bf(fmaf(a0.x + c0.x, rs, cc));
      fr.u[1] = f2bf(fmaf(a0.y + c0.y, rs, cc));
      fr.u[2] = f2bf(fmaf(a0.z + c0.z, rs, cc));
      fr.u[3] = f2bf(fmaf(a0.w + c0.w, rs, cc));
      fr.u[4] = f2bf(fmaf(a1.x + c1.x, rs, cc));
      fr.u[5] = f2bf(fmaf(a1.y + c1.y, rs, cc));
      fr.u[6] = f2bf(fmaf(a1.z + c1.z, rs, cc));
      fr.u[7] = f2bf(fmaf(a1.w + c1.w, rs, cc));
      afrag[g][ks] = fr.v;
    }
  }

  // ---- main loop: 32 chunks; order = barrier -> compute(s) -> stage(s+2) ----
  // Chunk s staged at iter s-2, force-drained by iter s-1's barrier (one compute window of
  // slack). After each barrier vmem-outstanding == 0, so ds_reads get no vmcnt wait.
  float oa[2][4][2] = {};
  for (int s = 0; s < 32; ++s) {
    __syncthreads();
    const short8* bf8 = s_frag[s & 3];
    f32x4 acc0 = {0.f, 0.f, 0.f, 0.f};
    f32x4 acc1 = {0.f, 0.f, 0.f, 0.f};
#pragma unroll
    for (int ks = 0; ks < 8; ++ks) {
      short8 bf = bf8[ks * 64 + lane];
      acc0 = __builtin_amdgcn_mfma_f32_16x16x32_bf16(afrag[0][ks], bf, acc0, 0, 0, 0);
      acc1 = __builtin_amdgcn_mfma_f32_16x16x32_bf16(afrag[1][ks], bf, acc1, 0, 0, 0);
    }
    if (s < 30) stage(s + 2, s_frag[(s + 2) & 3]);
    int e = s * 16 + n16;
    float bias = s_b1[e];
    float w0 = s_w2[2 * e], w1v = s_w2[2 * e + 1];
#pragma unroll
    for (int r = 0; r < 4; ++r) {
      float y0 = fmaxf(acc0[r] + bias, 0.f);
      float y1 = fmaxf(acc1[r] + bias, 0.f);
      oa[0][r][0] += y0 * w0; oa[0][r][1] += y0 * w1v;
      oa[1][r][0] += y1 * w0; oa[1][r][1] += y1 * w1v;
    }
  }

  // ---- reduce over the 16 column-lanes, stage, coalesced store ----
#pragma unroll
  for (int g = 0; g < 2; ++g)
#pragma unroll
    for (int r = 0; r < 4; ++r)
#pragma unroll
      for (int o = 0; o < 2; ++o) {
        float v = oa[g][r][o];
        v += __shfl_xor(v, 1);
        v += __shfl_xor(v, 2);
        v += __shfl_xor(v, 4);
        v += __shfl_xor(v, 8);
        oa[g][r][o] = v;
      }
  if (n16 == 0) {
#pragma unroll
    for (int g = 0; g < 2; ++g)
#pragma unroll
      for (int r = 0; r < 4; ++r) {
        int lrow = wave * 32 + g * 16 + quad * 4 + r;  // = f
        s_out[lrow * 2 + 0] = oa[g][r][0];
        s_out[lrow * 2 + 1] = oa[g][r][1];
      }
  }
  __syncthreads();
  out[bIdx * 256 + tid] = s_out[tid] + b2[tid & 1];
}

extern "C" void kernel_launch(void* const* d_in, const int* in_sizes, int n_in,
                              void* d_out, int out_size, void* d_ws, size_t ws_size,
                              hipStream_t stream) {
  const float* x = (const float*)d_in[0];
  const float* t_emb = (const float*)d_in[1];
  const float* f_emb = (const float*)d_in[2];
  const float* ln_g = (const float*)d_in[3];
  const float* ln_b = (const float*)d_in[4];
  const float* W1 = (const float*)d_in[5];
  const float* b1 = (const float*)d_in[6];
  const float* W2 = (const float*)d_in[7];
  const float* b2 = (const float*)d_in[8];

  unsigned short* w1t = (unsigned short*)d_ws;      // 512x256 bf16 = 256KB
  float* b1p = (float*)((char*)d_ws + 131072 * 2);  // 2KB

  prep<<<160, 256, 0, stream>>>(W1, ln_g, ln_b, b1, w1t, b1p);
  decoder_main<<<2048, 256, 0, stream>>>(x, t_emb, f_emb, w1t, b1p, W2, b2,
                                         (float*)d_out);
}